// Round 9
// baseline (856.568 us; speedup 1.0000x reference)
//
#include <hip/hip_runtime.h>
#include <hip/hip_bf16.h>

typedef unsigned int  uint32;
typedef unsigned short ushort16;
typedef __bf16 bfx8 __attribute__((ext_vector_type(8)));
typedef float  f32x4 __attribute__((ext_vector_type(4)));

typedef __attribute__((address_space(1))) const unsigned int gas_u32;
typedef __attribute__((address_space(3))) unsigned int las_u32;

#define B_   32
#define NQ_  300
#define D_   256
#define H_   8
#define HD_  32
#define L_   3
#define P_   4
#define S_   8400
#define FFN_ 1024
#define M1   (B_*NQ_)    // 9600
#define MV   (B_*S_)     // 268800
#define NQP  320
#define NQT  19

// ---------- helpers ----------
__device__ inline ushort16 f2bf(float x) {
  uint32 u = __float_as_uint(x);
  uint32 r = u + 0x7fffu + ((u >> 16) & 1u);
  return (ushort16)(r >> 16);
}
__device__ inline uint32 cvtpk(float lo, float hi) {
  uint32 r; asm("v_cvt_pk_bf16_f32 %0, %1, %2" : "=v"(r) : "v"(lo), "v"(hi)); return r;
}

// ---------- fused weight prep: chunk-major conversions + bias concats ----------
// image layout: chunk (kc,n) at ushort offset (kc*Nimg+n)*8; chunk j = W[(kc*8+j)*Nsrc + col]
struct WPrep {
  const float* srcA[8]; const float* srcB[8];
  ushort16*    dst[8];
  int K[8], Nimg[8], split[8], NsrcA[8], NsrcB[8], blkEnd[8];
  float scaleA[8];
  const float* bqs; const float* bks; float* bqk;
  const float* boffs; const float* baws; float* boffaw;
  float qscale;
};

__global__ __launch_bounds__(256) void rt_wprep(WPrep a)
{
  int blk = blockIdx.x;
  if (blk < 484) {
    int wi = 0;
    while (blk >= a.blkEnd[wi]) wi++;
    int base = wi ? a.blkEnd[wi - 1] : 0;
    int g = (blk - base) * 256 + threadIdx.x;
    int Nimg = a.Nimg[wi];
    int kc = g / Nimg, n = g - kc * Nimg;
    const float* src; int cs, Ns; float sc;
    if (n < a.split[wi]) { src = a.srcA[wi]; cs = n; Ns = a.NsrcA[wi]; sc = a.scaleA[wi]; }
    else                 { src = a.srcB[wi]; cs = n - a.split[wi]; Ns = a.NsrcB[wi]; sc = 1.f; }
    const float* p = src + (size_t)(kc * 8) * Ns + cs;
    uint4 u;
    u.x = (uint32)f2bf(p[0*Ns]*sc) | ((uint32)f2bf(p[1*Ns]*sc) << 16);
    u.y = (uint32)f2bf(p[2*Ns]*sc) | ((uint32)f2bf(p[3*Ns]*sc) << 16);
    u.z = (uint32)f2bf(p[4*Ns]*sc) | ((uint32)f2bf(p[5*Ns]*sc) << 16);
    u.w = (uint32)f2bf(p[6*Ns]*sc) | ((uint32)f2bf(p[7*Ns]*sc) << 16);
    *(uint4*)&a.dst[wi][(size_t)g * 8] = u;
  } else if (blk == 484) {
    a.bqk[threadIdx.x] = a.bqs[threadIdx.x] * a.qscale;
  } else if (blk == 485) {
    a.bqk[256 + threadIdx.x] = a.bks[threadIdx.x];
  } else if (blk == 486) {
    if (threadIdx.x < 192) a.boffaw[threadIdx.x] = a.boffs[threadIdx.x];
  } else {
    if (threadIdx.x < 96) a.boffaw[192 + threadIdx.x] = a.baws[threadIdx.x];
  }
}

// ---------- persistent value GEMM: B staged once in LDS, barrier-free tile loop ----------
__global__ __launch_bounds__(1024, 1) void rt_vgemm(
    const float* __restrict__ A, const ushort16* __restrict__ BC,
    const float* __restrict__ bias, ushort16* __restrict__ Vout)
{
  __shared__ __align__(16) char ldsB[131072];
  const int tid = threadIdx.x;
  const int lane = tid & 63, w = tid >> 6;
  const int l15 = lane & 15, l4 = lane >> 4;

#pragma unroll
  for (int i = 0; i < 8; ++i)
    __builtin_amdgcn_global_load_lds(
        (gas_u32*)(const void*)((const char*)BC + tid * 16 + i * 16384),
        (las_u32*)(void*)(&ldsB[tid * 16 + i * 16384]), 16, 0, 0);
  __syncthreads();

  const int wrow = w * 16 + l15;
  for (int t = blockIdx.x; t < MV / 256; t += 256) {
    const float* Ap = A + ((size_t)t * 256 + wrow) * 256 + l4 * 8;
    f32x4 aA = *(const f32x4*)(Ap);
    f32x4 aB = *(const f32x4*)(Ap + 4);
    f32x4 aC = *(const f32x4*)(Ap + 32);
    f32x4 aD = *(const f32x4*)(Ap + 36);
    f32x4 acc[16];
#pragma unroll
    for (int i = 0; i < 16; ++i) acc[i] = (f32x4){0.f, 0.f, 0.f, 0.f};

#pragma unroll
    for (int tt = 0; tt < 4; ++tt) {
      {
        uint4 u;
        u.x = cvtpk(aA[0], aA[1]); u.y = cvtpk(aA[2], aA[3]);
        u.z = cvtpk(aB[0], aB[1]); u.w = cvtpk(aB[2], aB[3]);
        bfx8 af = __builtin_bit_cast(bfx8, u);
        if (tt < 3) {
          aA = *(const f32x4*)(Ap + (2 * tt + 2) * 32);
          aB = *(const f32x4*)(Ap + (2 * tt + 2) * 32 + 4);
        }
        const char* bp = &ldsB[(2 * tt * 4 + l4) * 4096 + l15 * 16];
#pragma unroll
        for (int ni = 0; ni < 16; ++ni) {
          bfx8 bg = *(const bfx8*)(const void*)(bp + ni * 256);
          acc[ni] = __builtin_amdgcn_mfma_f32_16x16x32_bf16(bg, af, acc[ni], 0, 0, 0);
        }
      }
      {
        uint4 u;
        u.x = cvtpk(aC[0], aC[1]); u.y = cvtpk(aC[2], aC[3]);
        u.z = cvtpk(aD[0], aD[1]); u.w = cvtpk(aD[2], aD[3]);
        bfx8 af = __builtin_bit_cast(bfx8, u);
        if (tt < 3) {
          aC = *(const f32x4*)(Ap + (2 * tt + 3) * 32);
          aD = *(const f32x4*)(Ap + (2 * tt + 3) * 32 + 4);
        }
        const char* bp = &ldsB[((2 * tt + 1) * 4 + l4) * 4096 + l15 * 16];
#pragma unroll
        for (int ni = 0; ni < 16; ++ni) {
          bfx8 bg = *(const bfx8*)(const void*)(bp + ni * 256);
          acc[ni] = __builtin_amdgcn_mfma_f32_16x16x32_bf16(bg, af, acc[ni], 0, 0, 0);
        }
      }
    }
    int row = t * 256 + wrow;
    int bb = row / S_, s = row - bb * S_;
    ushort16* vb = Vout + (((size_t)bb * H_) * S_ + s) * HD_;
#pragma unroll
    for (int ni = 0; ni < 16; ++ni) {
      int col = ni * 16 + l4 * 4;
      f32x4 bv = *(const f32x4*)(bias + col);
      int hh = col >> 5, hd = col & 31;
      uint2 st;
      st.x = cvtpk(acc[ni][0] + bv[0], acc[ni][1] + bv[1]);
      st.y = cvtpk(acc[ni][2] + bv[2], acc[ni][3] + bv[3]);
      *(uint2*)(vb + (size_t)hh * S_ * HD_ + hd) = st;
    }
  }
}

// ---------- small-M streaming GEMM: LDS-free, barrier-free, B from L2 (chunk-major) ----------
// Block = 256 threads / 4 waves; wave = 16 rows x NB cols (NB = min(256, Nimg - bx*256)).
// mode 0: f32 C (stride Nc). mode 1: +relu. mode 3: bf16 scatter vh. mode 4: qk dual scatter.
__global__ __launch_bounds__(256) void rt_sgemm(
    const float* __restrict__ A, const float* __restrict__ A2,
    const ushort16* __restrict__ Wimg, const float* __restrict__ bias,
    float* __restrict__ C, ushort16* __restrict__ Sc, ushort16* __restrict__ Sc2,
    int Nimg, int K, int Nc, int mode)
{
  const int lane = threadIdx.x & 63, w = threadIdx.x >> 6;
  const int l15 = lane & 15, l4 = lane >> 4;
  const int n0 = blockIdx.x * 256;
  const int NB = min(256, Nimg - n0);
  const int row = blockIdx.y * 64 + w * 16 + l15;
  const int nk = K / 32;

  const float* Ap  = A + (size_t)row * K + l4 * 8;
  const float* Ap2 = A2 ? A2 + (size_t)row * K + l4 * 8 : nullptr;

  f32x4 acc[16];
#pragma unroll
  for (int i = 0; i < 16; ++i) acc[i] = (f32x4){0.f, 0.f, 0.f, 0.f};

  f32x4 a0 = *(const f32x4*)(Ap);
  f32x4 a1 = *(const f32x4*)(Ap + 4);
  if (A2) {
    f32x4 b0 = *(const f32x4*)(Ap2);
    f32x4 b1 = *(const f32x4*)(Ap2 + 4);
#pragma unroll
    for (int r = 0; r < 4; r++) { a0[r] += b0[r]; a1[r] += b1[r]; }
  }

  for (int t = 0; t < nk; ++t) {
    f32x4 p0 = {0.f,0.f,0.f,0.f}, p1 = {0.f,0.f,0.f,0.f};
    if (t + 1 < nk) {
      p0 = *(const f32x4*)(Ap + (t + 1) * 32);
      p1 = *(const f32x4*)(Ap + (t + 1) * 32 + 4);
      if (A2) {
        f32x4 q0 = *(const f32x4*)(Ap2 + (t + 1) * 32);
        f32x4 q1 = *(const f32x4*)(Ap2 + (t + 1) * 32 + 4);
#pragma unroll
        for (int r = 0; r < 4; r++) { p0[r] += q0[r]; p1[r] += q1[r]; }
      }
    }
    uint4 u;
    u.x = cvtpk(a0[0], a0[1]); u.y = cvtpk(a0[2], a0[3]);
    u.z = cvtpk(a1[0], a1[1]); u.w = cvtpk(a1[2], a1[3]);
    bfx8 af = __builtin_bit_cast(bfx8, u);
    const ushort16* bp = Wimg + ((size_t)(t * 4 + l4) * Nimg + n0 + l15) * 8;
#pragma unroll
    for (int ni = 0; ni < 16; ++ni) {
      if (ni * 16 < NB) {
        bfx8 bg = *(const bfx8*)(const void*)(bp + ni * 128);
        acc[ni] = __builtin_amdgcn_mfma_f32_16x16x32_bf16(bg, af, acc[ni], 0, 0, 0);
      }
    }
    a0 = p0; a1 = p1;
  }

  int bb = row / NQ_, q = row - bb * NQ_;
#pragma unroll
  for (int ni = 0; ni < 16; ++ni) {
    if (ni * 16 >= NB) continue;
    int col = n0 + ni * 16 + l4 * 4;
    f32x4 bv = *(const f32x4*)(bias + col);
    f32x4 vv;
#pragma unroll
    for (int r = 0; r < 4; r++) vv[r] = acc[ni][r] + bv[r];
    if (mode == 1) {
#pragma unroll
      for (int r = 0; r < 4; r++) vv[r] = fmaxf(vv[r], 0.f);
    }
    if (mode <= 1) {
      *(f32x4*)(C + (size_t)row * Nc + col) = vv;
    } else {
      int hh = col >> 5, hd = col & 31;
      ushort16* d = (mode == 3) ? Sc : ((hh < 8) ? Sc : Sc2);
      uint2 st;
      st.x = cvtpk(vv[0], vv[1]);
      st.y = cvtpk(vv[2], vv[3]);
      *(uint2*)(d + (((size_t)bb * H_ + (hh & 7)) * NQP + q) * HD_ + hd) = st;
    }
  }
}

// ---------- V transpose per (b,h) ----------
__global__ __launch_bounds__(256) void rt_vtr(const ushort16* __restrict__ vh,
                                              ushort16* __restrict__ vt)
{
  __shared__ ushort16 t[64][33];
  int bh = blockIdx.x;
  const ushort16* src = vh + (size_t)bh * NQP * HD_;
  ushort16* dst = vt + (size_t)bh * HD_ * NQP;
  int tid = threadIdx.x;
  int lrow = tid >> 2, lc8 = (tid & 3) * 8;
  int ohd = tid >> 3, oq8 = (tid & 7) * 8;
  for (int r0 = 0; r0 < NQP; r0 += 64) {
    uint4 v = *(const uint4*)(src + (size_t)(r0 + lrow) * HD_ + lc8);
    ushort16* tp = &t[lrow][lc8];
    tp[0] = (ushort16)(v.x & 0xffff); tp[1] = (ushort16)(v.x >> 16);
    tp[2] = (ushort16)(v.y & 0xffff); tp[3] = (ushort16)(v.y >> 16);
    tp[4] = (ushort16)(v.z & 0xffff); tp[5] = (ushort16)(v.z >> 16);
    tp[6] = (ushort16)(v.w & 0xffff); tp[7] = (ushort16)(v.w >> 16);
    __syncthreads();
    uint4 o;
    o.x = (uint32)t[oq8 + 0][ohd] | ((uint32)t[oq8 + 1][ohd] << 16);
    o.y = (uint32)t[oq8 + 2][ohd] | ((uint32)t[oq8 + 3][ohd] << 16);
    o.z = (uint32)t[oq8 + 4][ohd] | ((uint32)t[oq8 + 5][ohd] << 16);
    o.w = (uint32)t[oq8 + 6][ohd] | ((uint32)t[oq8 + 7][ohd] << 16);
    *(uint4*)(dst + (size_t)ohd * NQP + r0 + oq8) = o;
    __syncthreads();
  }
}

// ---------- MFMA flash self-attention ----------
__global__ __launch_bounds__(256) void rt_fattn(
    const ushort16* __restrict__ qh, const ushort16* __restrict__ kh,
    const ushort16* __restrict__ vt, float* __restrict__ O)
{
  int gw  = blockIdx.x * 4 + (threadIdx.x >> 6);
  int bh  = gw / NQT, qt = gw - bh * NQT;
  int b   = bh >> 3, h = bh & 7;
  int lane = threadIdx.x & 63;
  int l15 = lane & 15, l4 = lane >> 4;
  int kb4 = l4 * 4;
  const ushort16* Qb = qh + (size_t)bh * NQP * HD_;
  const ushort16* Kb = kh + (size_t)bh * NQP * HD_;
  const ushort16* Vb = vt + (size_t)bh * HD_ * NQP;
  int q = qt * 16 + l15;

  bfx8 bgQ = *(const bfx8*)(const void*)(Qb + (size_t)q * HD_ + l4 * 8);
  f32x4 o0 = {0.f,0.f,0.f,0.f}, o1 = {0.f,0.f,0.f,0.f};
  float m = -1e30f, ssum = 0.f;

  for (int k0 = 0; k0 < NQP; k0 += 32) {
    bfx8 afk0 = *(const bfx8*)(const void*)(Kb + (size_t)(k0 + l15) * HD_ + l4 * 8);
    bfx8 afk1 = *(const bfx8*)(const void*)(Kb + (size_t)(k0 + 16 + l15) * HD_ + l4 * 8);
    f32x4 z = {0.f,0.f,0.f,0.f};
    f32x4 s0 = __builtin_amdgcn_mfma_f32_16x16x32_bf16(afk0, bgQ, z, 0, 0, 0);
    f32x4 s1 = __builtin_amdgcn_mfma_f32_16x16x32_bf16(afk1, bgQ, z, 0, 0, 0);
    int ka = k0 + kb4, kbb = k0 + 16 + kb4;
#pragma unroll
    for (int r = 0; r < 4; r++) {
      if (ka  + r >= NQ_) s0[r] = -1e30f;
      if (kbb + r >= NQ_) s1[r] = -1e30f;
    }
    float cm = fmaxf(fmaxf(fmaxf(s0[0], s0[1]), fmaxf(s0[2], s0[3])),
                     fmaxf(fmaxf(s1[0], s1[1]), fmaxf(s1[2], s1[3])));
    cm = fmaxf(cm, __shfl_xor(cm, 16));
    cm = fmaxf(cm, __shfl_xor(cm, 32));
    float nm = fmaxf(m, cm);
    float sc = __expf(m - nm);
    m = nm;
    f32x4 p0, p1;
#pragma unroll
    for (int r = 0; r < 4; r++) { p0[r] = __expf(s0[r] - m); p1[r] = __expf(s1[r] - m); }
    float ls = (p0[0]+p0[1]+p0[2]+p0[3]) + (p1[0]+p1[1]+p1[2]+p1[3]);
    ls += __shfl_xor(ls, 16);
    ls += __shfl_xor(ls, 32);
    ssum = ssum * sc + ls;

    uint32 t0w0 = cvtpk(p0[0], p0[1]);
    uint32 t0w1 = cvtpk(p0[2], p0[3]);
    uint32 t1w0 = cvtpk(p1[0], p1[1]);
    uint32 t1w1 = cvtpk(p1[2], p1[3]);
    int srcA = l15 + 32 * (l4 & 1);
    int srcB = srcA + 16;
    uint32 a00 = __shfl((int)t0w0, srcA), a01 = __shfl((int)t0w1, srcA);
    uint32 b00 = __shfl((int)t0w0, srcB), b01 = __shfl((int)t0w1, srcB);
    uint32 a10 = __shfl((int)t1w0, srcA), a11 = __shfl((int)t1w1, srcA);
    uint32 b10 = __shfl((int)t1w0, srcB), b11 = __shfl((int)t1w1, srcB);
    bool hi = (l4 >= 2);
    uint4 pw;
    pw.x = hi ? a10 : a00;
    pw.y = hi ? a11 : a01;
    pw.z = hi ? b10 : b00;
    pw.w = hi ? b11 : b01;
    bfx8 bgP = __builtin_bit_cast(bfx8, pw);

    bfx8 afv0 = *(const bfx8*)(const void*)(Vb + (size_t)l15 * NQP + k0 + l4 * 8);
    bfx8 afv1 = *(const bfx8*)(const void*)(Vb + (size_t)(16 + l15) * NQP + k0 + l4 * 8);
#pragma unroll
    for (int r = 0; r < 4; r++) { o0[r] *= sc; o1[r] *= sc; }
    o0 = __builtin_amdgcn_mfma_f32_16x16x32_bf16(afv0, bgP, o0, 0, 0, 0);
    o1 = __builtin_amdgcn_mfma_f32_16x16x32_bf16(afv1, bgP, o1, 0, 0, 0);
  }

  if (q < NQ_) {
    float inv = 1.f / ssum;
    float* op = O + ((size_t)(b * NQ_ + q)) * D_ + h * HD_ + kb4;
    f32x4 r0, r1;
#pragma unroll
    for (int r = 0; r < 4; r++) { r0[r] = o0[r] * inv; r1[r] = o1[r] * inv; }
    *(f32x4*)op = r0;
    *(f32x4*)(op + 16) = r1;
  }
}

// ---------- LayerNorm ----------
__global__ __launch_bounds__(256) void rt_ln(
    const float* __restrict__ X, const float* __restrict__ R,
    const float* __restrict__ g, const float* __restrict__ be,
    float* __restrict__ O, int rows)
{
  int row = blockIdx.x * 4 + (threadIdx.x >> 6);
  int lane = threadIdx.x & 63;
  if (row >= rows) return;
  size_t base = (size_t)row * D_ + lane * 4;
  float4 x = *(const float4*)(X + base);
  float4 r = *(const float4*)(R + base);
  float v0 = x.x + r.x, v1 = x.y + r.y, v2 = x.z + r.z, v3 = x.w + r.w;
  float s = v0 + v1 + v2 + v3;
  float sq = v0*v0 + v1*v1 + v2*v2 + v3*v3;
#pragma unroll
  for (int o = 32; o >= 1; o >>= 1) { s += __shfl_xor(s, o); sq += __shfl_xor(sq, o); }
  float mean = s * (1.f / D_);
  float var  = sq * (1.f / D_) - mean * mean;
  float inv  = 1.f / sqrtf(var + 1e-5f);
  int c = lane * 4;
  float4 gv = *(const float4*)(g + c);
  float4 bv = *(const float4*)(be + c);
  float4 o4;
  o4.x = (v0 - mean) * inv * gv.x + bv.x;
  o4.y = (v1 - mean) * inv * gv.y + bv.y;
  o4.z = (v2 - mean) * inv * gv.z + bv.z;
  o4.w = (v3 - mean) * inv * gv.w + bv.w;
  *(float4*)(O + base) = o4;
}

// ---------- deformable sampling (aw softmax folded in) ----------
__device__ inline void rt_acc8(const ushort16* p, float wgt, float* acc) {
  uint4 v = *(const uint4*)(const void*)p;
  acc[0] += wgt * __uint_as_float(v.x << 16);
  acc[1] += wgt * __uint_as_float(v.x & 0xffff0000u);
  acc[2] += wgt * __uint_as_float(v.y << 16);
  acc[3] += wgt * __uint_as_float(v.y & 0xffff0000u);
  acc[4] += wgt * __uint_as_float(v.z << 16);
  acc[5] += wgt * __uint_as_float(v.z & 0xffff0000u);
  acc[6] += wgt * __uint_as_float(v.w << 16);
  acc[7] += wgt * __uint_as_float(v.w & 0xffff0000u);
}

__global__ __launch_bounds__(256) void rt_deform(
    const ushort16* __restrict__ value,
    const float* __restrict__ offaw,      // [B*NQ][288]
    const float* __restrict__ ref,
    float* __restrict__ O)
{
  int gid = blockIdx.x * 256 + threadIdx.x;
  int hd0 = (gid & 3) * 8;
  int bqh = gid >> 2;
  int h   = bqh & 7;
  int bq  = bqh >> 3;
  int b   = bq / NQ_;
  const float* rp = ref + (size_t)bq * 4;
  float rx = rp[0], ry = rp[1];
  float rw = rp[2] * 0.125f, rh = rp[3] * 0.125f;
  const float* op = offaw + (size_t)bq * 288 + h * 24;
  const float* ap = offaw + (size_t)bq * 288 + 192 + h * 12;
  float e[12]; float mx = -1e30f;
#pragma unroll
  for (int i = 0; i < 12; i++) { e[i] = ap[i]; mx = fmaxf(mx, e[i]); }
  float ssum = 0.f;
#pragma unroll
  for (int i = 0; i < 12; i++) { e[i] = __expf(e[i] - mx); ssum += e[i]; }
  float sinv = 1.f / ssum;

  const ushort16* vb = value + ((size_t)b * H_ + h) * (size_t)S_ * HD_ + hd0;
  float acc[8];
#pragma unroll
  for (int i = 0; i < 8; i++) acc[i] = 0.f;
  const int starts[3] = {0, 6400, 8000};
  const int dims[3]   = {80, 40, 20};
#pragma unroll
  for (int l = 0; l < L_; l++) {
    const int Wl = dims[l];
    const ushort16* vl = vb + (size_t)starts[l] * HD_;
#pragma unroll
    for (int p = 0; p < P_; p++) {
      int ip = l * P_ + p;
      float wgt = e[ip] * sinv;
      float x = (rx + op[ip*2+0] * rw) * Wl - 0.5f;
      float y = (ry + op[ip*2+1] * rh) * Wl - 0.5f;
      float x0f = floorf(x), y0f = floorf(y);
      int   x0 = (int)x0f,  y0 = (int)y0f;
      float wx1 = x - x0f, wy1 = y - y0f;
      float wx0 = 1.f - wx1, wy0 = 1.f - wy1;
      bool xok0 = (x0 >= 0) & (x0 < Wl), xok1 = (x0+1 >= 0) & (x0+1 < Wl);
      bool yok0 = (y0 >= 0) & (y0 < Wl), yok1 = (y0+1 >= 0) & (y0+1 < Wl);
      const ushort16* r0p = vl + (size_t)(y0 * Wl) * HD_;
      const ushort16* r1p = r0p + (size_t)Wl * HD_;
      if (xok0 & yok0) rt_acc8(r0p + (size_t)x0 * HD_,     wgt * wx0 * wy0, acc);
      if (xok1 & yok0) rt_acc8(r0p + (size_t)(x0+1) * HD_, wgt * wx1 * wy0, acc);
      if (xok0 & yok1) rt_acc8(r1p + (size_t)x0 * HD_,     wgt * wx0 * wy1, acc);
      if (xok1 & yok1) rt_acc8(r1p + (size_t)(x0+1) * HD_, wgt * wx1 * wy1, acc);
    }
  }
  float* outp = O + (size_t)bq * D_ + h * HD_ + hd0;
  float4 a0, a1;
  a0.x = acc[0]; a0.y = acc[1]; a0.z = acc[2]; a0.w = acc[3];
  a1.x = acc[4]; a1.y = acc[5]; a1.z = acc[6]; a1.w = acc[7];
  *(float4*)outp = a0;
  *(float4*)(outp + 4) = a1;
}

// ---------- launch ----------
extern "C" void kernel_launch(void* const* d_in, const int* in_sizes, int n_in,
                              void* d_out, int out_size, void* d_ws, size_t ws_size,
                              hipStream_t stream)
{
  const float* hs   = (const float*)d_in[0];
  const float* pos  = (const float*)d_in[1];
  const float* ref  = (const float*)d_in[2];
  const float* ehs  = (const float*)d_in[3];
  const float* Wq   = (const float*)d_in[4];
  const float* Wk   = (const float*)d_in[5];
  const float* Wv   = (const float*)d_in[6];
  const float* Wo   = (const float*)d_in[7];
  const float* Woff = (const float*)d_in[8];
  const float* Waw  = (const float*)d_in[9];
  const float* Wval = (const float*)d_in[10];
  const float* Wout = (const float*)d_in[11];
  const float* W1   = (const float*)d_in[12];
  const float* W2   = (const float*)d_in[13];
  const float* bq   = (const float*)d_in[14];
  const float* bk   = (const float*)d_in[15];
  const float* bvv  = (const float*)d_in[16];
  const float* bo   = (const float*)d_in[17];
  const float* boff = (const float*)d_in[18];
  const float* baw  = (const float*)d_in[19];
  const float* bval = (const float*)d_in[20];
  const float* bout = (const float*)d_in[21];
  const float* b1   = (const float*)d_in[22];
  const float* b2   = (const float*)d_in[23];
  const float* ln1g = (const float*)d_in[24];
  const float* ln1b = (const float*)d_in[25];
  const float* ln2g = (const float*)d_in[26];
  const float* ln2b = (const float*)d_in[27];
  const float* ln3g = (const float*)d_in[28];
  const float* ln3b = (const float*)d_in[29];
  float* out = (float*)d_out;

  float* ws = (float*)d_ws;
  ushort16* value = (ushort16*)ws;                 // [B][H][S][HD] bf16
  float* t0     = ws + 34406400;
  float* t1     = ws + 36864000;
  float* hs1    = ws + 39321600;
  float* hs2    = ws + 41779200;
  float* offawb = ws + 44236800;                   // [M1][288]
  float* ffn1   = ws + 47001600;                   // [M1][1024]
  ushort16* qh = (ushort16*)(ws + 56832000);
  ushort16* kh = (ushort16*)(ws + 58142720);
  ushort16* vh = (ushort16*)(ws + 59453440);
  ushort16* vt = (ushort16*)(ws + 60764160);
  ushort16* WqkC   = (ushort16*)(ws + 62074880);   // 32kc x 512
  ushort16* WvC    = (ushort16*)(ws + 62140416);   // 32 x 256
  ushort16* WoC    = (ushort16*)(ws + 62173184);
  ushort16* WoffawC= (ushort16*)(ws + 62205952);   // 32 x 288
  ushort16* WoutC  = (ushort16*)(ws + 62242816);
  ushort16* W1C    = (ushort16*)(ws + 62275584);   // 32 x 1024
  ushort16* W2C    = (ushort16*)(ws + 62406656);   // 128kc x 256
  ushort16* WvalC  = (ushort16*)(ws + 62537728);
  float* bqk    = ws + 62570496;                   // [512]
  float* boffaw = ws + 62571008;                   // [288]

  const float qscale = 0.17677669529663687f;

  WPrep a;
  // 0: WqkC (Wq scaled | Wk)
  a.srcA[0]=Wq;   a.srcB[0]=Wk;  a.dst[0]=WqkC;    a.K[0]=256;  a.Nimg[0]=512;  a.split[0]=256; a.NsrcA[0]=256;  a.NsrcB[0]=256; a.scaleA[0]=qscale;
  a.srcA[1]=Wv;   a.srcB[1]=Wv;  a.dst[1]=WvC;     a.K[1]=256;  a.Nimg[1]=256;  a.split[1]=256; a.NsrcA[1]=256;  a.NsrcB[1]=256; a.scaleA[1]=1.f;
  a.srcA[2]=Wo;   a.srcB[2]=Wo;  a.dst[2]=WoC;     a.K[2]=256;  a.Nimg[2]=256;  a.split[2]=256; a.NsrcA[2]=256;  a.NsrcB[2]=256; a.scaleA[2]=1.f;
  a.srcA[3]=Woff; a.srcB[3]=Waw; a.dst[3]=WoffawC; a.K[3]=256;  a.Nimg[3]=288;  a.split[3]=192; a.NsrcA[3]=192;  a.NsrcB[3]=96;  a.scaleA[3]=1.f;
  a.srcA[4]=Wout; a.srcB[4]=Wout;a.dst[4]=WoutC;   a.K[4]=256;  a.Nimg[4]=256;  a.split[4]=256; a.NsrcA[4]=256;  a.NsrcB[4]=256; a.scaleA[4]=1.f;
  a.srcA[5]=W1;   a.srcB[5]=W1;  a.dst[5]=W1C;     a.K[5]=256;  a.Nimg[5]=1024; a.split[5]=1024;a.NsrcA[5]=1024; a.NsrcB[5]=1024;a.scaleA[5]=1.f;
  a.srcA[6]=W2;   a.srcB[6]=W2;  a.dst[6]=W2C;     a.K[6]=1024; a.Nimg[6]=256;  a.split[6]=256; a.NsrcA[6]=256;  a.NsrcB[6]=256; a.scaleA[6]=1.f;
  a.srcA[7]=Wval; a.srcB[7]=Wval;a.dst[7]=WvalC;   a.K[7]=256;  a.Nimg[7]=256;  a.split[7]=256; a.NsrcA[7]=256;  a.NsrcB[7]=256; a.scaleA[7]=1.f;
  int cum = 0;
  int blks[8] = {64, 32, 32, 36, 32, 128, 128, 32};   // (K/8)*Nimg/256
  for (int i = 0; i < 8; i++) { cum += blks[i]; a.blkEnd[i] = cum; }   // 484
  a.bqs = bq; a.bks = bk; a.bqk = bqk;
  a.boffs = boff; a.baws = baw; a.boffaw = boffaw; a.qscale = qscale;
  rt_wprep<<<dim3(488), 256, 0, stream>>>(a);

  // value projection (persistent, whole-B-in-LDS)
  rt_vgemm<<<dim3(256), 1024, 0, stream>>>(ehs, WvalC, bval, value);

  // q+k fused projection (hs+pos on the fly), v projection
  rt_sgemm<<<dim3(2, 150), 256, 0, stream>>>(hs, pos, WqkC, bqk, nullptr, qh, kh, 512, 256, 0, 4);
  rt_sgemm<<<dim3(1, 150), 256, 0, stream>>>(hs, nullptr, WvC, bvv, nullptr, vh, nullptr, 256, 256, 0, 3);
  rt_vtr<<<dim3(B_*H_), 256, 0, stream>>>(vh, vt);
  rt_fattn<<<dim3(B_*H_*NQT/4), 256, 0, stream>>>(qh, kh, vt, t0);
  rt_sgemm<<<dim3(1, 150), 256, 0, stream>>>(t0, nullptr, WoC, bo, t1, nullptr, nullptr, 256, 256, 256, 0);
  rt_ln<<<dim3(M1/4), 256, 0, stream>>>(hs, t1, ln1g, ln1b, hs1, M1);
  // off+aw fused projection (hs1+pos on the fly)
  rt_sgemm<<<dim3(2, 150), 256, 0, stream>>>(hs1, pos, WoffawC, boffaw, offawb, nullptr, nullptr, 288, 256, 288, 0);
  rt_deform<<<dim3(M1*H_*4/256), 256, 0, stream>>>(value, offawb, ref, t0);
  rt_sgemm<<<dim3(1, 150), 256, 0, stream>>>(t0, nullptr, WoutC, bout, t1, nullptr, nullptr, 256, 256, 256, 0);
  rt_ln<<<dim3(M1/4), 256, 0, stream>>>(hs1, t1, ln2g, ln2b, hs2, M1);
  rt_sgemm<<<dim3(4, 150), 256, 0, stream>>>(hs2, nullptr, W1C, b1, ffn1, nullptr, nullptr, 1024, 256, 1024, 1);
  rt_sgemm<<<dim3(1, 150), 256, 0, stream>>>(ffn1, nullptr, W2C, b2, t1, nullptr, nullptr, 256, 1024, 256, 0);
  rt_ln<<<dim3(M1/4), 256, 0, stream>>>(hs2, t1, ln3g, ln3b, out, M1);
}

// Round 10
// 394.080 us; speedup vs baseline: 2.1736x; 2.1736x over previous
//
#include <hip/hip_runtime.h>
#include <hip/hip_bf16.h>

typedef unsigned int  uint32;
typedef unsigned short ushort16;
typedef __bf16 bfx8 __attribute__((ext_vector_type(8)));
typedef float  f32x4 __attribute__((ext_vector_type(4)));

typedef __attribute__((address_space(1))) const unsigned int gas_u32;
typedef __attribute__((address_space(3))) unsigned int las_u32;

#define B_   32
#define NQ_  300
#define D_   256
#define H_   8
#define HD_  32
#define L_   3
#define P_   4
#define S_   8400
#define FFN_ 1024
#define M1   (B_*NQ_)    // 9600
#define MV   (B_*S_)     // 268800
#define NQP  320
#define NQT  19

// ---------- helpers ----------
__device__ inline ushort16 f2bf(float x) {
  uint32 u = __float_as_uint(x);
  uint32 r = u + 0x7fffu + ((u >> 16) & 1u);
  return (ushort16)(r >> 16);
}
__device__ inline uint32 cvtpk(float lo, float hi) {
  uint32 r; asm("v_cvt_pk_bf16_f32 %0, %1, %2" : "=v"(r) : "v"(lo), "v"(hi)); return r;
}

// ---------- fused weight prep (R8 version): transposes + Wval chunk-major + bias concats ----------
struct WPrep {
  const float* src[9];
  ushort16*    dst[9];
  int K[9], N[9], Npad[9], tileEnd[9];
  float scale[9];
  const float* wval; ushort16* wvalc;
  const float* bqs;  const float* bks;  float* bqk;
  const float* boffs; const float* baws; float* boffaw;
};

__global__ __launch_bounds__(256) void rt_wprep(WPrep a)
{
  __shared__ float t[32][33];
  int blk = blockIdx.x;
  if (blk < 904) {
    int wi = 0;
    while (blk >= a.tileEnd[wi]) wi++;
    int base = wi ? a.tileEnd[wi - 1] : 0;
    int idx = blk - base;
    int K = a.K[wi], N = a.N[wi];
    int ntx = a.Npad[wi] / 32;
    int n0 = (idx % ntx) * 32, k0 = (idx / ntx) * 32;
    float sc = a.scale[wi];
    const float* W = a.src[wi];
    ushort16* WT = a.dst[wi];
    int c = threadIdx.x & 31, r = threadIdx.x >> 5;
#pragma unroll
    for (int i = 0; i < 4; i++) {
      int nn = n0 + c;
      t[r + i * 8][c] = (nn < N) ? W[(size_t)(k0 + r + i * 8) * N + nn] : 0.f;
    }
    __syncthreads();
#pragma unroll
    for (int i = 0; i < 4; i++)
      WT[(size_t)(n0 + r + i * 8) * K + k0 + c] = f2bf(t[c][r + i * 8] * sc);
  } else if (blk < 936) {
    int gid = (blk - 904) * 256 + threadIdx.x;
    int c = gid >> 8, n = gid & 255;
    const float* W = a.wval;
    uint4 u;
    u.x = (uint32)f2bf(W[(c*8+0)*256 + n]) | ((uint32)f2bf(W[(c*8+1)*256 + n]) << 16);
    u.y = (uint32)f2bf(W[(c*8+2)*256 + n]) | ((uint32)f2bf(W[(c*8+3)*256 + n]) << 16);
    u.z = (uint32)f2bf(W[(c*8+4)*256 + n]) | ((uint32)f2bf(W[(c*8+5)*256 + n]) << 16);
    u.w = (uint32)f2bf(W[(c*8+6)*256 + n]) | ((uint32)f2bf(W[(c*8+7)*256 + n]) << 16);
    *(uint4*)&a.wvalc[(size_t)c * 2048 + n * 8] = u;
  } else if (blk == 936) {
    a.bqk[threadIdx.x] = a.bqs[threadIdx.x] * a.scale[0];
  } else if (blk == 937) {
    a.bqk[256 + threadIdx.x] = a.bks[threadIdx.x];
  } else if (blk == 938) {
    if (threadIdx.x < 192) a.boffaw[threadIdx.x] = a.boffs[threadIdx.x];
  } else {
    if (threadIdx.x < 96) a.boffaw[192 + threadIdx.x] = a.baws[threadIdx.x];
  }
}

// ---------- persistent value GEMM (R8 version): B staged once, barrier-free tile loop ----------
__global__ __launch_bounds__(1024, 1) void rt_vgemm(
    const float* __restrict__ A, const ushort16* __restrict__ BC,
    const float* __restrict__ bias, ushort16* __restrict__ Vout)
{
  __shared__ __align__(16) char ldsB[131072];
  const int tid = threadIdx.x;
  const int lane = tid & 63, w = tid >> 6;
  const int l15 = lane & 15, l4 = lane >> 4;

#pragma unroll
  for (int i = 0; i < 8; ++i)
    __builtin_amdgcn_global_load_lds(
        (gas_u32*)(const void*)((const char*)BC + tid * 16 + i * 16384),
        (las_u32*)(void*)(&ldsB[tid * 16 + i * 16384]), 16, 0, 0);
  __syncthreads();

  const int wrow = w * 16 + l15;
  for (int t = blockIdx.x; t < MV / 256; t += 256) {
    const float* Ap = A + ((size_t)t * 256 + wrow) * 256 + l4 * 8;
    f32x4 aA = *(const f32x4*)(Ap);
    f32x4 aB = *(const f32x4*)(Ap + 4);
    f32x4 aC = *(const f32x4*)(Ap + 32);
    f32x4 aD = *(const f32x4*)(Ap + 36);
    f32x4 acc[16];
#pragma unroll
    for (int i = 0; i < 16; ++i) acc[i] = (f32x4){0.f, 0.f, 0.f, 0.f};

#pragma unroll
    for (int tt = 0; tt < 4; ++tt) {
      {
        uint4 u;
        u.x = cvtpk(aA[0], aA[1]); u.y = cvtpk(aA[2], aA[3]);
        u.z = cvtpk(aB[0], aB[1]); u.w = cvtpk(aB[2], aB[3]);
        bfx8 af = __builtin_bit_cast(bfx8, u);
        if (tt < 3) {
          aA = *(const f32x4*)(Ap + (2 * tt + 2) * 32);
          aB = *(const f32x4*)(Ap + (2 * tt + 2) * 32 + 4);
        }
        const char* bp = &ldsB[(2 * tt * 4 + l4) * 4096 + l15 * 16];
#pragma unroll
        for (int ni = 0; ni < 16; ++ni) {
          bfx8 bg = *(const bfx8*)(const void*)(bp + ni * 256);
          acc[ni] = __builtin_amdgcn_mfma_f32_16x16x32_bf16(bg, af, acc[ni], 0, 0, 0);
        }
      }
      {
        uint4 u;
        u.x = cvtpk(aC[0], aC[1]); u.y = cvtpk(aC[2], aC[3]);
        u.z = cvtpk(aD[0], aD[1]); u.w = cvtpk(aD[2], aD[3]);
        bfx8 af = __builtin_bit_cast(bfx8, u);
        if (tt < 3) {
          aC = *(const f32x4*)(Ap + (2 * tt + 3) * 32);
          aD = *(const f32x4*)(Ap + (2 * tt + 3) * 32 + 4);
        }
        const char* bp = &ldsB[((2 * tt + 1) * 4 + l4) * 4096 + l15 * 16];
#pragma unroll
        for (int ni = 0; ni < 16; ++ni) {
          bfx8 bg = *(const bfx8*)(const void*)(bp + ni * 256);
          acc[ni] = __builtin_amdgcn_mfma_f32_16x16x32_bf16(bg, af, acc[ni], 0, 0, 0);
        }
      }
    }
    int row = t * 256 + wrow;
    int bb = row / S_, s = row - bb * S_;
    ushort16* vb = Vout + (((size_t)bb * H_) * S_ + s) * HD_;
#pragma unroll
    for (int ni = 0; ni < 16; ++ni) {
      int col = ni * 16 + l4 * 4;
      f32x4 bv = *(const f32x4*)(bias + col);
      int hh = col >> 5, hd = col & 31;
      uint2 st;
      st.x = cvtpk(acc[ni][0] + bv[0], acc[ni][1] + bv[1]);
      st.y = cvtpk(acc[ni][2] + bv[2], acc[ni][3] + bv[3]);
      *(uint2*)(vb + (size_t)hh * S_ * HD_ + hd) = st;
    }
  }
}

// ---------- MFMA bf16 GEMM (R8 structure + pos-fusion + z-axis K-split) ----------
// mode 0: f32 C. mode 1: f32 C + relu. mode 3: bf16 scatter [b][h][NQP][hd].
// mode 4: dual scatter (cols 0..255 -> Sc=qh, 256..511 -> Sc2=kh).
// gridDim.z = K-split count; block z writes C (z=0, with bias) or C2 (z=1, no bias).
#define GBM 128
#define GBN 128
#define GBK 32
#define LDP 40

__global__ __launch_bounds__(256) void rt_mgemm(
    const float* __restrict__ A, const float* __restrict__ A2,
    const ushort16* __restrict__ BT, const float* __restrict__ bias,
    float* __restrict__ C, float* __restrict__ C2,
    ushort16* __restrict__ Sc, ushort16* __restrict__ Sc2,
    int M, int N, int K, int klen, float scale, int mode)
{
  __shared__ __align__(16) ushort16 As[GBM][LDP];
  __shared__ __align__(16) ushort16 Bs[GBN][LDP];
  const int tid  = threadIdx.x;
  const int lane = tid & 63;
  const int w    = tid >> 6;
  const int wr   = (w >> 1) * 64;
  const int wc   = (w & 1) * 64;
  const int bm   = blockIdx.y * GBM;
  const int bn   = blockIdx.x * GBN;
  const int kz   = blockIdx.z;
  const int kb   = kz * klen;
  const int l15  = lane & 15;
  const int l4   = lane >> 4;

  f32x4 acc[4][4];
#pragma unroll
  for (int i = 0; i < 4; i++)
#pragma unroll
    for (int j = 0; j < 4; j++)
      acc[i][j] = (f32x4){0.f, 0.f, 0.f, 0.f};

  const int arow = tid >> 3, akc = tid & 7;
  const int brow = tid >> 2, bkc = tid & 3;

  for (int k0 = kb; k0 < kb + klen; k0 += GBK) {
#pragma unroll
    for (int i = 0; i < 4; i++) {
      int row = arow + i * 32;
      f32x4 v = *(const f32x4*)(A + (size_t)(bm + row) * K + k0 + akc * 4);
      if (A2) {
        f32x4 v2 = *(const f32x4*)(A2 + (size_t)(bm + row) * K + k0 + akc * 4);
#pragma unroll
        for (int r = 0; r < 4; r++) v[r] += v2[r];
      }
      uint2 u;
      u.x = cvtpk(v.x, v.y);
      u.y = cvtpk(v.z, v.w);
      *(uint2*)(&As[row][akc * 4]) = u;
    }
#pragma unroll
    for (int i = 0; i < 2; i++) {
      int row = brow + i * 64;
      uint4 v = *(const uint4*)(BT + (size_t)(bn + row) * K + k0 + bkc * 8);
      *(uint4*)(&Bs[row][bkc * 8]) = v;
    }
    __syncthreads();

    bfx8 af[4], bg[4];
#pragma unroll
    for (int mi = 0; mi < 4; mi++)
      af[mi] = *(const bfx8*)(&As[wr + mi * 16 + l15][l4 * 8]);
#pragma unroll
    for (int ni = 0; ni < 4; ni++)
      bg[ni] = *(const bfx8*)(&Bs[wc + ni * 16 + l15][l4 * 8]);
#pragma unroll
    for (int mi = 0; mi < 4; mi++)
#pragma unroll
      for (int ni = 0; ni < 4; ni++)
        acc[mi][ni] = __builtin_amdgcn_mfma_f32_16x16x32_bf16(af[mi], bg[ni], acc[mi][ni], 0, 0, 0);
    __syncthreads();
  }

  float* Cp = kz ? C2 : C;
#pragma unroll
  for (int mi = 0; mi < 4; mi++) {
#pragma unroll
    for (int ni = 0; ni < 4; ni++) {
      int col = bn + wc + ni * 16 + l15;
      if (col >= N) continue;
      float bv = kz ? 0.f : bias[col];
#pragma unroll
      for (int r = 0; r < 4; r++) {
        int row = bm + wr + mi * 16 + l4 * 4 + r;
        float vv = (acc[mi][ni][r] + bv) * scale;
        if (mode == 1) vv = fmaxf(vv, 0.f);
        if (mode == 3) {
          int bb = row / NQ_, q = row - bb * NQ_;
          int hh = col >> 5, hd = col & 31;
          Sc[(((size_t)bb * H_ + hh) * NQP + q) * HD_ + hd] = f2bf(vv);
        } else if (mode == 4) {
          int bb = row / NQ_, q = row - bb * NQ_;
          int hh = col >> 5, hd = col & 31;
          ushort16* d = (hh < 8) ? Sc : Sc2;
          d[(((size_t)bb * H_ + (hh & 7)) * NQP + q) * HD_ + hd] = f2bf(vv);
        } else {
          Cp[(size_t)row * N + col] = vv;
        }
      }
    }
  }
}

// ---------- V transpose per (b,h) ----------
__global__ __launch_bounds__(256) void rt_vtr(const ushort16* __restrict__ vh,
                                              ushort16* __restrict__ vt)
{
  __shared__ ushort16 t[64][33];
  int bh = blockIdx.x;
  const ushort16* src = vh + (size_t)bh * NQP * HD_;
  ushort16* dst = vt + (size_t)bh * HD_ * NQP;
  int tid = threadIdx.x;
  int lrow = tid >> 2, lc8 = (tid & 3) * 8;
  int ohd = tid >> 3, oq8 = (tid & 7) * 8;
  for (int r0 = 0; r0 < NQP; r0 += 64) {
    uint4 v = *(const uint4*)(src + (size_t)(r0 + lrow) * HD_ + lc8);
    ushort16* tp = &t[lrow][lc8];
    tp[0] = (ushort16)(v.x & 0xffff); tp[1] = (ushort16)(v.x >> 16);
    tp[2] = (ushort16)(v.y & 0xffff); tp[3] = (ushort16)(v.y >> 16);
    tp[4] = (ushort16)(v.z & 0xffff); tp[5] = (ushort16)(v.z >> 16);
    tp[6] = (ushort16)(v.w & 0xffff); tp[7] = (ushort16)(v.w >> 16);
    __syncthreads();
    uint4 o;
    o.x = (uint32)t[oq8 + 0][ohd] | ((uint32)t[oq8 + 1][ohd] << 16);
    o.y = (uint32)t[oq8 + 2][ohd] | ((uint32)t[oq8 + 3][ohd] << 16);
    o.z = (uint32)t[oq8 + 4][ohd] | ((uint32)t[oq8 + 5][ohd] << 16);
    o.w = (uint32)t[oq8 + 6][ohd] | ((uint32)t[oq8 + 7][ohd] << 16);
    *(uint4*)(dst + (size_t)ohd * NQP + r0 + oq8) = o;
    __syncthreads();
  }
}

// ---------- MFMA flash self-attention ----------
__global__ __launch_bounds__(256) void rt_fattn(
    const ushort16* __restrict__ qh, const ushort16* __restrict__ kh,
    const ushort16* __restrict__ vt, float* __restrict__ O)
{
  int gw  = blockIdx.x * 4 + (threadIdx.x >> 6);
  int bh  = gw / NQT, qt = gw - bh * NQT;
  int b   = bh >> 3, h = bh & 7;
  int lane = threadIdx.x & 63;
  int l15 = lane & 15, l4 = lane >> 4;
  int kb4 = l4 * 4;
  const ushort16* Qb = qh + (size_t)bh * NQP * HD_;
  const ushort16* Kb = kh + (size_t)bh * NQP * HD_;
  const ushort16* Vb = vt + (size_t)bh * HD_ * NQP;
  int q = qt * 16 + l15;

  bfx8 bgQ = *(const bfx8*)(const void*)(Qb + (size_t)q * HD_ + l4 * 8);
  f32x4 o0 = {0.f,0.f,0.f,0.f}, o1 = {0.f,0.f,0.f,0.f};
  float m = -1e30f, ssum = 0.f;

  for (int k0 = 0; k0 < NQP; k0 += 32) {
    bfx8 afk0 = *(const bfx8*)(const void*)(Kb + (size_t)(k0 + l15) * HD_ + l4 * 8);
    bfx8 afk1 = *(const bfx8*)(const void*)(Kb + (size_t)(k0 + 16 + l15) * HD_ + l4 * 8);
    f32x4 z = {0.f,0.f,0.f,0.f};
    f32x4 s0 = __builtin_amdgcn_mfma_f32_16x16x32_bf16(afk0, bgQ, z, 0, 0, 0);
    f32x4 s1 = __builtin_amdgcn_mfma_f32_16x16x32_bf16(afk1, bgQ, z, 0, 0, 0);
    int ka = k0 + kb4, kbb = k0 + 16 + kb4;
#pragma unroll
    for (int r = 0; r < 4; r++) {
      if (ka  + r >= NQ_) s0[r] = -1e30f;
      if (kbb + r >= NQ_) s1[r] = -1e30f;
    }
    float cm = fmaxf(fmaxf(fmaxf(s0[0], s0[1]), fmaxf(s0[2], s0[3])),
                     fmaxf(fmaxf(s1[0], s1[1]), fmaxf(s1[2], s1[3])));
    cm = fmaxf(cm, __shfl_xor(cm, 16));
    cm = fmaxf(cm, __shfl_xor(cm, 32));
    float nm = fmaxf(m, cm);
    float sc = __expf(m - nm);
    m = nm;
    f32x4 p0, p1;
#pragma unroll
    for (int r = 0; r < 4; r++) { p0[r] = __expf(s0[r] - m); p1[r] = __expf(s1[r] - m); }
    float ls = (p0[0]+p0[1]+p0[2]+p0[3]) + (p1[0]+p1[1]+p1[2]+p1[3]);
    ls += __shfl_xor(ls, 16);
    ls += __shfl_xor(ls, 32);
    ssum = ssum * sc + ls;

    uint32 t0w0 = cvtpk(p0[0], p0[1]);
    uint32 t0w1 = cvtpk(p0[2], p0[3]);
    uint32 t1w0 = cvtpk(p1[0], p1[1]);
    uint32 t1w1 = cvtpk(p1[2], p1[3]);
    int srcA = l15 + 32 * (l4 & 1);
    int srcB = srcA + 16;
    uint32 a00 = __shfl((int)t0w0, srcA), a01 = __shfl((int)t0w1, srcA);
    uint32 b00 = __shfl((int)t0w0, srcB), b01 = __shfl((int)t0w1, srcB);
    uint32 a10 = __shfl((int)t1w0, srcA), a11 = __shfl((int)t1w1, srcA);
    uint32 b10 = __shfl((int)t1w0, srcB), b11 = __shfl((int)t1w1, srcB);
    bool hi = (l4 >= 2);
    uint4 pw;
    pw.x = hi ? a10 : a00;
    pw.y = hi ? a11 : a01;
    pw.z = hi ? b10 : b00;
    pw.w = hi ? b11 : b01;
    bfx8 bgP = __builtin_bit_cast(bfx8, pw);

    bfx8 afv0 = *(const bfx8*)(const void*)(Vb + (size_t)l15 * NQP + k0 + l4 * 8);
    bfx8 afv1 = *(const bfx8*)(const void*)(Vb + (size_t)(16 + l15) * NQP + k0 + l4 * 8);
#pragma unroll
    for (int r = 0; r < 4; r++) { o0[r] *= sc; o1[r] *= sc; }
    o0 = __builtin_amdgcn_mfma_f32_16x16x32_bf16(afv0, bgP, o0, 0, 0, 0);
    o1 = __builtin_amdgcn_mfma_f32_16x16x32_bf16(afv1, bgP, o1, 0, 0, 0);
  }

  if (q < NQ_) {
    float inv = 1.f / ssum;
    float* op = O + ((size_t)(b * NQ_ + q)) * D_ + h * HD_ + kb4;
    f32x4 r0, r1;
#pragma unroll
    for (int r = 0; r < 4; r++) { r0[r] = o0[r] * inv; r1[r] = o1[r] * inv; }
    *(f32x4*)op = r0;
    *(f32x4*)(op + 16) = r1;
  }
}

// ---------- LayerNorm with two residual inputs: O = LN(X + R1 + R2)*g + b ----------
__global__ __launch_bounds__(256) void rt_ln2(
    const float* __restrict__ X, const float* __restrict__ R1,
    const float* __restrict__ R2,
    const float* __restrict__ g, const float* __restrict__ be,
    float* __restrict__ O, int rows)
{
  int row = blockIdx.x * 4 + (threadIdx.x >> 6);
  int lane = threadIdx.x & 63;
  if (row >= rows) return;
  size_t base = (size_t)row * D_ + lane * 4;
  float4 x = *(const float4*)(X + base);
  float4 r = *(const float4*)(R1 + base);
  float v0 = x.x + r.x, v1 = x.y + r.y, v2 = x.z + r.z, v3 = x.w + r.w;
  if (R2) {
    float4 r2 = *(const float4*)(R2 + base);
    v0 += r2.x; v1 += r2.y; v2 += r2.z; v3 += r2.w;
  }
  float s = v0 + v1 + v2 + v3;
  float sq = v0*v0 + v1*v1 + v2*v2 + v3*v3;
#pragma unroll
  for (int o = 32; o >= 1; o >>= 1) { s += __shfl_xor(s, o); sq += __shfl_xor(sq, o); }
  float mean = s * (1.f / D_);
  float var  = sq * (1.f / D_) - mean * mean;
  float inv  = 1.f / sqrtf(var + 1e-5f);
  int c = lane * 4;
  float4 gv = *(const float4*)(g + c);
  float4 bv = *(const float4*)(be + c);
  float4 o4;
  o4.x = (v0 - mean) * inv * gv.x + bv.x;
  o4.y = (v1 - mean) * inv * gv.y + bv.y;
  o4.z = (v2 - mean) * inv * gv.z + bv.z;
  o4.w = (v3 - mean) * inv * gv.w + bv.w;
  *(float4*)(O + base) = o4;
}

// ---------- deformable sampling (aw softmax folded in) ----------
__device__ inline void rt_acc8(const ushort16* p, float wgt, float* acc) {
  uint4 v = *(const uint4*)(const void*)p;
  acc[0] += wgt * __uint_as_float(v.x << 16);
  acc[1] += wgt * __uint_as_float(v.x & 0xffff0000u);
  acc[2] += wgt * __uint_as_float(v.y << 16);
  acc[3] += wgt * __uint_as_float(v.y & 0xffff0000u);
  acc[4] += wgt * __uint_as_float(v.z << 16);
  acc[5] += wgt * __uint_as_float(v.z & 0xffff0000u);
  acc[6] += wgt * __uint_as_float(v.w << 16);
  acc[7] += wgt * __uint_as_float(v.w & 0xffff0000u);
}

__global__ __launch_bounds__(256) void rt_deform(
    const ushort16* __restrict__ value,
    const float* __restrict__ offaw,      // [B*NQ][288]
    const float* __restrict__ ref,
    float* __restrict__ O)
{
  int gid = blockIdx.x * 256 + threadIdx.x;
  int hd0 = (gid & 3) * 8;
  int bqh = gid >> 2;
  int h   = bqh & 7;
  int bq  = bqh >> 3;
  int b   = bq / NQ_;
  const float* rp = ref + (size_t)bq * 4;
  float rx = rp[0], ry = rp[1];
  float rw = rp[2] * 0.125f, rh = rp[3] * 0.125f;
  const float* op = offaw + (size_t)bq * 288 + h * 24;
  const float* ap = offaw + (size_t)bq * 288 + 192 + h * 12;
  float e[12]; float mx = -1e30f;
#pragma unroll
  for (int i = 0; i < 12; i++) { e[i] = ap[i]; mx = fmaxf(mx, e[i]); }
  float ssum = 0.f;
#pragma unroll
  for (int i = 0; i < 12; i++) { e[i] = __expf(e[i] - mx); ssum += e[i]; }
  float sinv = 1.f / ssum;

  const ushort16* vb = value + ((size_t)b * H_ + h) * (size_t)S_ * HD_ + hd0;
  float acc[8];
#pragma unroll
  for (int i = 0; i < 8; i++) acc[i] = 0.f;
  const int starts[3] = {0, 6400, 8000};
  const int dims[3]   = {80, 40, 20};
#pragma unroll
  for (int l = 0; l < L_; l++) {
    const int Wl = dims[l];
    const ushort16* vl = vb + (size_t)starts[l] * HD_;
#pragma unroll
    for (int p = 0; p < P_; p++) {
      int ip = l * P_ + p;
      float wgt = e[ip] * sinv;
      float x = (rx + op[ip*2+0] * rw) * Wl - 0.5f;
      float y = (ry + op[ip*2+1] * rh) * Wl - 0.5f;
      float x0f = floorf(x), y0f = floorf(y);
      int   x0 = (int)x0f,  y0 = (int)y0f;
      float wx1 = x - x0f, wy1 = y - y0f;
      float wx0 = 1.f - wx1, wy0 = 1.f - wy1;
      bool xok0 = (x0 >= 0) & (x0 < Wl), xok1 = (x0+1 >= 0) & (x0+1 < Wl);
      bool yok0 = (y0 >= 0) & (y0 < Wl), yok1 = (y0+1 >= 0) & (y0+1 < Wl);
      const ushort16* r0p = vl + (size_t)(y0 * Wl) * HD_;
      const ushort16* r1p = r0p + (size_t)Wl * HD_;
      if (xok0 & yok0) rt_acc8(r0p + (size_t)x0 * HD_,     wgt * wx0 * wy0, acc);
      if (xok1 & yok0) rt_acc8(r0p + (size_t)(x0+1) * HD_, wgt * wx1 * wy0, acc);
      if (xok0 & yok1) rt_acc8(r1p + (size_t)x0 * HD_,     wgt * wx0 * wy1, acc);
      if (xok1 & yok1) rt_acc8(r1p + (size_t)(x0+1) * HD_, wgt * wx1 * wy1, acc);
    }
  }
  float* outp = O + (size_t)bq * D_ + h * HD_ + hd0;
  float4 a0, a1;
  a0.x = acc[0]; a0.y = acc[1]; a0.z = acc[2]; a0.w = acc[3];
  a1.x = acc[4]; a1.y = acc[5]; a1.z = acc[6]; a1.w = acc[7];
  *(float4*)outp = a0;
  *(float4*)(outp + 4) = a1;
}

// ---------- launch ----------
extern "C" void kernel_launch(void* const* d_in, const int* in_sizes, int n_in,
                              void* d_out, int out_size, void* d_ws, size_t ws_size,
                              hipStream_t stream)
{
  const float* hs   = (const float*)d_in[0];
  const float* pos  = (const float*)d_in[1];
  const float* ref  = (const float*)d_in[2];
  const float* ehs  = (const float*)d_in[3];
  const float* Wq   = (const float*)d_in[4];
  const float* Wk   = (const float*)d_in[5];
  const float* Wv   = (const float*)d_in[6];
  const float* Wo   = (const float*)d_in[7];
  const float* Woff = (const float*)d_in[8];
  const float* Waw  = (const float*)d_in[9];
  const float* Wval = (const float*)d_in[10];
  const float* Wout = (const float*)d_in[11];
  const float* W1   = (const float*)d_in[12];
  const float* W2   = (const float*)d_in[13];
  const float* bq   = (const float*)d_in[14];
  const float* bk   = (const float*)d_in[15];
  const float* bvv  = (const float*)d_in[16];
  const float* bo   = (const float*)d_in[17];
  const float* boff = (const float*)d_in[18];
  const float* baw  = (const float*)d_in[19];
  const float* bval = (const float*)d_in[20];
  const float* bout = (const float*)d_in[21];
  const float* b1   = (const float*)d_in[22];
  const float* b2   = (const float*)d_in[23];
  const float* ln1g = (const float*)d_in[24];
  const float* ln1b = (const float*)d_in[25];
  const float* ln2g = (const float*)d_in[26];
  const float* ln2b = (const float*)d_in[27];
  const float* ln3g = (const float*)d_in[28];
  const float* ln3b = (const float*)d_in[29];
  float* out = (float*)d_out;

  float* ws = (float*)d_ws;
  ushort16* value = (ushort16*)ws;                 // [B][H][S][HD] bf16
  float* t2     = ws + 34406400;                   // K-split partial
  float* t0     = ws + 36864000;
  float* t1     = ws + 39321600;
  float* hs1    = ws + 41779200;
  float* hs2    = ws + 44236800;
  float* offawb = ws + 46694400;                   // [M1][288]
  float* ffn1   = ws + 49459200;                   // [M1][1024]
  ushort16* qh = (ushort16*)(ws + 59289600);
  ushort16* kh = (ushort16*)(ws + 60600320);
  ushort16* vh = (ushort16*)(ws + 61911040);
  ushort16* vt = (ushort16*)(ws + 63221760);
  ushort16* wbase  = (ushort16*)(ws + 64532480);
  ushort16* WqkT   = wbase;                        // [512][256]
  ushort16* WvT    = WqkT   + 131072;
  ushort16* WoT    = WvT    + 65536;
  ushort16* WoffawT= WoT    + 65536;               // [288][256]
  ushort16* WoutT  = WoffawT+ 98304;
  ushort16* W1T    = WoutT  + 65536;               // [1024][256]
  ushort16* W2T    = W1T    + 262144;              // [256][1024]
  ushort16* WvalC  = W2T    + 262144;              // chunk-major
  float* bqk    = (float*)(WvalC + 65536);         // [512]
  float* boffaw = bqk + 512;                       // [288]

  const float qscale = 0.17677669529663687f;

  WPrep a;
  a.src[0]=Wq;   a.dst[0]=WqkT;            a.K[0]=256;  a.N[0]=256;  a.Npad[0]=256; a.scale[0]=qscale;
  a.src[1]=Wk;   a.dst[1]=WqkT+65536;      a.K[1]=256;  a.N[1]=256;  a.Npad[1]=256; a.scale[1]=1.f;
  a.src[2]=Wv;   a.dst[2]=WvT;             a.K[2]=256;  a.N[2]=256;  a.Npad[2]=256; a.scale[2]=1.f;
  a.src[3]=Wo;   a.dst[3]=WoT;             a.K[3]=256;  a.N[3]=256;  a.Npad[3]=256; a.scale[3]=1.f;
  a.src[4]=Woff; a.dst[4]=WoffawT;         a.K[4]=256;  a.N[4]=192;  a.Npad[4]=192; a.scale[4]=1.f;
  a.src[5]=Waw;  a.dst[5]=WoffawT+49152;   a.K[5]=256;  a.N[5]=96;   a.Npad[5]=96;  a.scale[5]=1.f;
  a.src[6]=Wout; a.dst[6]=WoutT;           a.K[6]=256;  a.N[6]=256;  a.Npad[6]=256; a.scale[6]=1.f;
  a.src[7]=W1;   a.dst[7]=W1T;             a.K[7]=256;  a.N[7]=1024; a.Npad[7]=1024;a.scale[7]=1.f;
  a.src[8]=W2;   a.dst[8]=W2T;             a.K[8]=1024; a.N[8]=256;  a.Npad[8]=256; a.scale[8]=1.f;
  int cum = 0;
  int tiles[9] = {64, 64, 64, 64, 48, 24, 64, 256, 256};
  for (int i = 0; i < 9; i++) { cum += tiles[i]; a.tileEnd[i] = cum; }   // 904
  a.wval = Wval; a.wvalc = WvalC;
  a.bqs = bq; a.bks = bk; a.bqk = bqk;
  a.boffs = boff; a.baws = baw; a.boffaw = boffaw;
  rt_wprep<<<dim3(940), 256, 0, stream>>>(a);

  // value projection: persistent, B-in-LDS once
  rt_vgemm<<<dim3(256), 1024, 0, stream>>>(ehs, WvalC, bval, value);

  // q+k fused projection (pos fused into A-staging); v projection
  rt_mgemm<<<dim3(4, M1/GBM, 1), 256, 0, stream>>>(hs, pos, WqkT, bqk, nullptr, nullptr, qh, kh, M1, 512, 256, 256, 1.f, 4);
  rt_mgemm<<<dim3(2, M1/GBM, 1), 256, 0, stream>>>(hs, nullptr, WvT, bvv, nullptr, nullptr, vh, nullptr, M1, 256, 256, 256, 1.f, 3);
  rt_vtr<<<dim3(B_*H_), 256, 0, stream>>>(vh, vt);
  rt_fattn<<<dim3(B_*H_*NQT/4), 256, 0, stream>>>(qh, kh, vt, t0);
  // Wo projection: K-split 2 (z-axis), partials t1 + t2, merged in LN1
  rt_mgemm<<<dim3(2, M1/GBM, 2), 256, 0, stream>>>(t0, nullptr, WoT, bo, t1, t2, nullptr, nullptr, M1, 256, 256, 128, 1.f, 0);
  rt_ln2<<<dim3(M1/4), 256, 0, stream>>>(hs, t1, t2, ln1g, ln1b, hs1, M1);
  // off+aw fused projection (pos fused)
  rt_mgemm<<<dim3(3, M1/GBM, 1), 256, 0, stream>>>(hs1, pos, WoffawT, boffaw, offawb, nullptr, nullptr, nullptr, M1, 288, 256, 256, 1.f, 0);
  rt_deform<<<dim3(M1*H_*4/256), 256, 0, stream>>>(value, offawb, ref, t0);
  // Wout projection: K-split 2
  rt_mgemm<<<dim3(2, M1/GBM, 2), 256, 0, stream>>>(t0, nullptr, WoutT, bout, t1, t2, nullptr, nullptr, M1, 256, 256, 128, 1.f, 0);
  rt_ln2<<<dim3(M1/4), 256, 0, stream>>>(hs1, t1, t2, ln2g, ln2b, hs2, M1);
  // FFN
  rt_mgemm<<<dim3(8, M1/GBM, 1), 256, 0, stream>>>(hs2, nullptr, W1T, b1, ffn1, nullptr, nullptr, nullptr, M1, FFN_, 256, 256, 1.f, 1);
  // W2: K-split 2 (K=1024 -> 512 each)
  rt_mgemm<<<dim3(2, M1/GBM, 2), 256, 0, stream>>>(ffn1, nullptr, W2T, b2, t1, t2, nullptr, nullptr, M1, 256, 1024, 512, 1.f, 0);
  rt_ln2<<<dim3(M1/4), 256, 0, stream>>>(hs2, t1, t2, ln3g, ln3b, out, M1);
}